// Round 5
// baseline (911.716 us; speedup 1.0000x reference)
//
#include <hip/hip_runtime.h>
#include <stdint.h>

#define TT 4096
#define HID 7168
#define QL 1536
#define NH 64
#define HD 128
#define QD 8192
#define KTOP 2048
#define WSCALE 0.011048543456039806f

typedef _Float16 f16;
typedef uint16_t u16;
typedef unsigned u32;
typedef __attribute__((ext_vector_type(4))) float f32x4;
typedef __attribute__((ext_vector_type(16))) float f32x16;
typedef __attribute__((ext_vector_type(8))) _Float16 f16x8;
typedef __attribute__((ext_vector_type(4))) _Float16 f16x4;

__device__ __forceinline__ void lds_load16(const void* g, void* l) {
  __builtin_amdgcn_global_load_lds(
      (const __attribute__((address_space(1))) unsigned*)g,
      (__attribute__((address_space(3))) unsigned*)l, 16, 0, 0);
}

__device__ __forceinline__ u16 f16_bits(f16 h) {
  union { f16 h; u16 u; } c; c.h = h; return c.u;
}
__device__ __forceinline__ float f16_from_bits(u16 u) {
  union { u16 u; f16 h; } c; c.u = u; return (float)c.h;
}

// packed-triangular row offset (elements); each row t gets roundup(t+1,128) slots.
__device__ __forceinline__ size_t soff(int t) {
  int b = t >> 7, r = t & 127;
  return (size_t)128u * ((size_t)(b + 1) * (size_t)(64 * b + r));
}

// ---------------- tiled transpose f32[R][C] -> f16 out[(c+orow0)][r] ----------------
__global__ void tcvt(const float* __restrict__ in, f16* __restrict__ out,
                     int R, int C, int ostride, int orow0) {
  __shared__ float tile[32][33];
  int cb = blockIdx.x * 32, rb = blockIdx.y * 32;
  int tx = threadIdx.x & 31, ty = threadIdx.x >> 5;  // ty 0..7
  for (int i = 0; i < 32; i += 8)
    tile[ty + i][tx] = in[(size_t)(rb + ty + i) * C + cb + tx];
  __syncthreads();
  for (int i = 0; i < 32; i += 8)
    out[(size_t)(cb + ty + i + orow0) * ostride + rb + tx] = (f16)tile[tx][ty + i];
}

// ---------------- q16 = f16(qr @ Wq_b)  (A fp32 via ds_write staging, B f16; 128x128, BK=32) ----------------
__launch_bounds__(256, 2)
__global__ void gemm_q(const float* __restrict__ A, const f16* __restrict__ B, f16* __restrict__ C) {
  __shared__ __align__(16) f16 As[128 * 32];
  __shared__ __align__(16) f16 Bs[128 * 32];
  int tid = threadIdx.x, lane = tid & 63, wave = tid >> 6;
  int bm = blockIdx.y << 7, bn = blockIdx.x << 7;
  int wm = (wave & 1) << 6, wn = (wave >> 1) << 6;
  const f16* gb = B + (size_t)(bn + (tid >> 2)) * QL + (tid & 3) * 8;
  f16* lB = Bs + wave * 512;
  int ar = tid >> 3, ac = (tid & 7) * 4;
  f32x4 acc[4][4] = {};
  for (int k0 = 0; k0 < QL; k0 += 32) {
    __syncthreads();
#pragma unroll
    for (int i = 0; i < 4; i++) {
      float4 v = *(const float4*)(A + (size_t)(bm + ar + i * 32) * QL + k0 + ac);
      f16x4 h = {(f16)v.x, (f16)v.y, (f16)v.z, (f16)v.w};
      *(f16x4*)(As + (ar + i * 32) * 32 + ac) = h;
    }
    lds_load16(gb + k0, lB);
    lds_load16(gb + (size_t)64 * QL + k0, lB + 2048);
    __syncthreads();
    int ro = lane & 15, ko = (lane >> 4) << 3;
    f16x8 af[4], bf[4];
#pragma unroll
    for (int i = 0; i < 4; i++) af[i] = *(const f16x8*)(As + (wm + i * 16 + ro) * 32 + ko);
#pragma unroll
    for (int i = 0; i < 4; i++) bf[i] = *(const f16x8*)(Bs + (wn + i * 16 + ro) * 32 + ko);
#pragma unroll
    for (int mi = 0; mi < 4; mi++)
#pragma unroll
      for (int ni = 0; ni < 4; ni++)
        acc[mi][ni] = __builtin_amdgcn_mfma_f32_16x16x32_f16(af[mi], bf[ni], acc[mi][ni], 0, 0, 0);
  }
  int cr = (lane >> 4) << 2, cc = lane & 15;
#pragma unroll
  for (int mi = 0; mi < 4; mi++)
#pragma unroll
    for (int ni = 0; ni < 4; ni++) {
      int row = bm + wm + mi * 16 + cr;
      int col = bn + wn + ni * 16 + cc;
      f16* cp = C + (size_t)row * QD + col;
#pragma unroll
      for (int r = 0; r < 4; r++) cp[(size_t)r * QD] = (f16)acc[mi][ni][r];
    }
}

// ---------------- [kraw | w] = hs @ [Wk | Wproj]  (A fp32 via ds_write staging; 64x64, BK=64) ----------------
__launch_bounds__(256, 2)
__global__ void gemm_kw(const float* __restrict__ A, const f16* __restrict__ B,
                        float* __restrict__ kraw, float* __restrict__ wout) {
  __shared__ __align__(16) f16 As[64 * 64];
  __shared__ __align__(16) f16 Bs[64 * 64];
  int tid = threadIdx.x, lane = tid & 63, wave = tid >> 6;
  int bm = blockIdx.y << 6, bn = blockIdx.x << 6;
  int wm = (wave & 1) << 5, wn = (wave >> 1) << 5;
  const f16* gb = B + (size_t)(bn + (tid >> 3)) * HID + (tid & 7) * 8;
  f16* lB = Bs + wave * 512;
  int ar = tid >> 4, ac = (tid & 15) * 4;
  f32x4 acc[2][2] = {};
  for (int k0 = 0; k0 < HID; k0 += 64) {
    __syncthreads();
#pragma unroll
    for (int i = 0; i < 4; i++) {
      float4 v = *(const float4*)(A + (size_t)(bm + ar + i * 16) * HID + k0 + ac);
      f16x4 h = {(f16)v.x, (f16)v.y, (f16)v.z, (f16)v.w};
      *(f16x4*)(As + (ar + i * 16) * 64 + ac) = h;
    }
    lds_load16(gb + k0, lB);
    lds_load16(gb + (size_t)32 * HID + k0, lB + 2048);
    __syncthreads();
    int ro = lane & 15, ko = (lane >> 4) << 3;
    f16x8 af[2][2], bf[2][2];
#pragma unroll
    for (int i = 0; i < 2; i++)
#pragma unroll
      for (int kk = 0; kk < 2; kk++) {
        af[i][kk] = *(const f16x8*)(As + (wm + i * 16 + ro) * 64 + kk * 32 + ko);
        bf[i][kk] = *(const f16x8*)(Bs + (wn + i * 16 + ro) * 64 + kk * 32 + ko);
      }
#pragma unroll
    for (int mi = 0; mi < 2; mi++)
#pragma unroll
      for (int ni = 0; ni < 2; ni++)
#pragma unroll
        for (int kk = 0; kk < 2; kk++)
          acc[mi][ni] = __builtin_amdgcn_mfma_f32_16x16x32_f16(af[mi][kk], bf[ni][kk], acc[mi][ni], 0, 0, 0);
  }
  int cr = (lane >> 4) << 2, cc = lane & 15;
#pragma unroll
  for (int mi = 0; mi < 2; mi++)
#pragma unroll
    for (int ni = 0; ni < 2; ni++) {
      int row = bm + wm + mi * 16 + cr;
      int col = bn + wn + ni * 16 + cc;
#pragma unroll
      for (int r = 0; r < 4; r++) {
        float v = acc[mi][ni][r];
        int rr = row + r;
        if (col < HD) kraw[(size_t)rr * HD + col] = v;
        else          wout[(size_t)rr * NH + (col - HD)] = v * WSCALE;
      }
    }
}

// ---------------- layernorm + rope on k -> f16 ----------------
__global__ void ln_rope(const float* __restrict__ kraw, const int* __restrict__ pos,
                        const float* __restrict__ gamma, const float* __restrict__ beta,
                        f16* __restrict__ k16) {
  int row = (blockIdx.x << 2) + (threadIdx.x >> 6);
  int lane = threadIdx.x & 63;
  const float* kr = kraw + (size_t)row * HD;
  float2 x = ((const float2*)kr)[lane];
  float s = x.x + x.y, s2 = x.x * x.x + x.y * x.y;
  for (int off = 32; off; off >>= 1) { s += __shfl_down(s, off); s2 += __shfl_down(s2, off); }
  s = __shfl(s, 0); s2 = __shfl(s2, 0);
  float mu = s * (1.f / 128.f);
  float var = s2 * (1.f / 128.f) - mu * mu;
  float inv = rsqrtf(var + 1e-6f);
  float y0 = (x.x - mu) * inv * gamma[lane * 2] + beta[lane * 2];
  float y1 = (x.y - mu) * inv * gamma[lane * 2 + 1] + beta[lane * 2 + 1];
  float o0 = y0, o1 = y1;
  if (lane < 32) {
    float p = (float)pos[row];
    float invf = exp2f(-(float)lane * 0.41524101185942813f);  // 10000^(-2l/64)
    float ang = p * invf;
    float sn, cn;
    sincosf(ang, &sn, &cn);
    o0 = y0 * cn - y1 * sn;
    o1 = y0 * sn + y1 * cn;
  }
  k16[(size_t)row * HD + 2 * lane] = (f16)o0;
  k16[(size_t)row * HD + 2 * lane + 1] = (f16)o1;
}

// ---------------- rope on q16 in place (dims 0..63 of each head) ----------------
__global__ void rope_q(f16* __restrict__ q16, const int* __restrict__ pos) {
  int t = blockIdx.x, tid = threadIdx.x;
  __shared__ float cs[64];
  if (tid < 32) {
    float invf = exp2f(-(float)tid * 0.41524101185942813f);
    float ang = (float)pos[t] * invf;
    float sn, cn;
    sincosf(ang, &sn, &cn);
    cs[tid] = cn;
    cs[32 + tid] = sn;
  }
  __syncthreads();
  f16* row = q16 + (size_t)t * QD;
#pragma unroll
  for (int it = 0; it < 2; it++) {
    int u = it * 256 + tid;
    int h = u >> 3, c = u & 7;     // 64 heads x 8 chunks of 16B (dims 0..63)
    f16* p = row + h * HD + c * 8;
    f16x8 v = *(f16x8*)p;
#pragma unroll
    for (int j = 0; j < 4; j++) {
      int l = c * 4 + j;
      float cn = cs[l], sn = cs[32 + l];
      float x = (float)v[2 * j], y = (float)v[2 * j + 1];
      v[2 * j] = (f16)(x * cn - y * sn);
      v[2 * j + 1] = (f16)(x * sn + y * cn);
    }
    *(f16x8*)p = v;
  }
}

// ---------------- scores GEMM v4: 32 queries x 256 keys per block; NO barriers in main loop ----
// K-frags in regs (64 keys/wave); Q loaded global->regs per head, double-buffered (qa/qb named).
// Each wave is an independent dataflow stream; L1/L2 serve the shared 8KB/head Q slices.
// S stored f16 in packed-triangular rows (row t gets roundup(t+1,128) slots).
__launch_bounds__(256, 2)
__global__ void scores4(const f16* __restrict__ q16, const f16* __restrict__ k16,
                        const float* __restrict__ w, f16* __restrict__ S) {
  // compact enumeration of active (qt,kt) pairs + XCD-chunked bijective swizzle (1088 = 8*136)
  int bid = (int)blockIdx.x;
  bid = (bid & 7) * 136 + (bid >> 3);
  int g = 0;
  while (4 * (g + 1) * (g + 2) <= bid) g++;   // group g: qt in [8g,8g+7], each with g+1 key tiles
  int rem = bid - 4 * g * (g + 1);
  int qt = (g << 3) + rem / (g + 1);
  int kt = rem - (rem / (g + 1)) * (g + 1);
  int kt0 = kt << 8, qt0 = qt << 5;

  int tid = threadIdx.x, l = tid & 63, wid = tid >> 6;
  int q = l & 31, half = l >> 5;
  __shared__ __align__(16) unsigned char smem[16384];  // w_lds (8KB) in main loop; 16KB store tile after
  float* w_lds = (float*)smem;                         // w[h][q] transposed

  for (int i = tid; i < 2048; i += 256) {
    int hh = i & 63, qq = i >> 6;
    w_lds[hh * 32 + qq] = w[(size_t)(qt0 + qq) * NH + hh];
  }
  // K fragments into registers: wave wid owns keys kt0 + wid*64 .. +63 (2 M-tiles of 32)
  f16x8 kfr[2][8];
  {
    const f16* kb = k16 + (size_t)(kt0 + wid * 64 + q) * HD + half * 8;
#pragma unroll
    for (int mt = 0; mt < 2; mt++)
#pragma unroll
      for (int kk = 0; kk < 8; kk++)
        kfr[mt][kk] = *(const f16x8*)(kb + mt * 32 * HD + kk * 16);
  }
  __syncthreads();  // w_lds visible

  // per-lane Q fragment base: row (qt0+q), k-dims half*8.. ; per head offset h*HD
  const f16* qrow = q16 + (size_t)(qt0 + q) * QD + half * 8;
  f16x8 qa[8], qb[8];
#pragma unroll
  for (int kk = 0; kk < 8; kk++) qa[kk] = *(const f16x8*)(qrow + kk * 16);

  f32x16 s0 = {}, s1 = {};
  auto compute = [&](const f16x8 (&qf)[8], int h) {
    float wv = w_lds[h * 32 + q];
    f32x16 a0 = {}, a1 = {};
    __builtin_amdgcn_s_setprio(1);
#pragma unroll
    for (int kk = 0; kk < 8; kk++) {
      a0 = __builtin_amdgcn_mfma_f32_32x32x16_f16(kfr[0][kk], qf[kk], a0, 0, 0, 0);
      a1 = __builtin_amdgcn_mfma_f32_32x32x16_f16(kfr[1][kk], qf[kk], a1, 0, 0, 0);
    }
    __builtin_amdgcn_s_setprio(0);
#pragma unroll
    for (int r = 0; r < 16; r++) {
      s0[r] += wv * fmaxf(a0[r], 0.f);
      s1[r] += wv * fmaxf(a1[r], 0.f);
    }
  };

  for (int h = 0; h < NH; h += 2) {
    const f16* src1 = qrow + (size_t)(h + 1) * HD;
#pragma unroll
    for (int kk = 0; kk < 8; kk++) qb[kk] = *(const f16x8*)(src1 + kk * 16);
    compute(qa, h);          // overlaps qb loads
    if (h + 2 < NH) {
      const f16* src2 = qrow + (size_t)(h + 2) * HD;
#pragma unroll
      for (int kk = 0; kk < 8; kk++) qa[kk] = *(const f16x8*)(src2 + kk * 16);
    }
    compute(qb, h + 1);      // overlaps qa loads
  }
  __syncthreads();  // all w_lds reads done before the store tile overwrites smem

  // epilogue: transpose through LDS (XOR-swizzled [32 q][256 sl] f16) then coalesced stores
  f16* st = (f16*)smem;
#pragma unroll
  for (int mt = 0; mt < 2; mt++)
#pragma unroll
    for (int r = 0; r < 16; r++) {
      int m = (r & 3) + ((r >> 2) << 3) + half * 4;  // key row within 32x32 tile
      int sl = wid * 64 + mt * 32 + m;
      float v = mt ? s1[r] : s0[r];
      if (!(v == v)) v = 0.f;                        // NaN scrub
      v = fminf(fmaxf(v, -60000.f), 60000.f);        // keep f16-finite
      u32 byte = (u32)(q * 512 + sl * 2) ^ (u32)((q & 7) << 4);
      *(f16*)((char*)st + byte) = (f16)v;
    }
  __syncthreads();
  {
    int rq = tid >> 3, c = tid & 7;    // 32 rows x 8 chunks of 64B
    int t = qt0 + rq;
    size_t base = soff(t) + (size_t)kt0;
    bool hi = (t - kt0) >= 128;        // whether cols 128..255 fit this row's slot
#pragma unroll
    for (int j = 0; j < 4; j++) {
      if (c < 4 || hi) {
        u32 byte = (u32)(rq * 512 + c * 64 + j * 16) ^ (u32)((rq & 7) << 4);
        uint4 v = *(uint4*)((char*)st + byte);
        *(uint4*)(S + base + c * 32 + j * 8) = v;
      }
    }
  }
}

// ---------------- register-resident bitonic sort (ascending on ~key) + store ----------------
template <int N>
__device__ __forceinline__ void sort_and_store(u32* key, int tid, int t, float* out) {
  constexpr int V = N / 256;  // 8 or 16 keys per thread
  u32 v[V];
#pragma unroll
  for (int r = 0; r < V; r += 4) {
    uint4 q4 = *(const uint4*)(key + tid * V + r);
    v[r] = ~q4.x; v[r + 1] = ~q4.y; v[r + 2] = ~q4.z; v[r + 3] = ~q4.w;
  }
#pragma unroll
  for (int k = 2; k <= N; k <<= 1) {
#pragma unroll
    for (int j = k >> 1; j > 0; j >>= 1) {
      if (j >= 64 * V) {
        // cross-wave pass via LDS
#pragma unroll
        for (int r = 0; r < V; r += 4) {
          uint4 q4 = {v[r], v[r + 1], v[r + 2], v[r + 3]};
          *(uint4*)(key + tid * V + r) = q4;
        }
        __syncthreads();
        for (int m = tid; m < N / 2; m += 256) {
          int i = ((m & ~(j - 1)) << 1) | (m & (j - 1));
          int l = i | j;
          bool up = ((i & k) == 0);
          u32 a = key[i], b = key[l];
          if (up ? (a > b) : (a < b)) { key[i] = b; key[l] = a; }
        }
        __syncthreads();
#pragma unroll
        for (int r = 0; r < V; r += 4) {
          uint4 q4 = *(const uint4*)(key + tid * V + r);
          v[r] = q4.x; v[r + 1] = q4.y; v[r + 2] = q4.z; v[r + 3] = q4.w;
        }
      } else if (j >= V) {
        // cross-lane pass via shuffle
        int lanej = j / V;
        bool takeMin = (((tid & lanej) == 0) == (((tid * V) & k) == 0));
#pragma unroll
        for (int r = 0; r < V; r++) {
          u32 o = __shfl_xor(v[r], lanej, 64);
          u32 mn = min(v[r], o), mx = max(v[r], o);
          v[r] = takeMin ? mn : mx;
        }
      } else {
        // intra-thread pass: pure VALU
#pragma unroll
        for (int r = 0; r < V; r++) {
          if ((r & j) == 0) {
            bool up = (((tid * V + r) & k) == 0);
            u32 a = v[r], b = v[r | j];
            u32 mn = min(a, b), mx = max(a, b);
            v[r] = up ? mn : mx;
            v[r | j] = up ? mx : mn;
          }
        }
      }
    }
  }
  // elements 0..KTOP-1 (ascending ~key = descending key) -> output
  if (tid * V < KTOP) {
    float* ov = out + (size_t)t * KTOP + tid * V;
    float* oi = out + (size_t)TT * KTOP + (size_t)t * KTOP + tid * V;
#pragma unroll
    for (int r = 0; r < V; r++) {
      u32 kv = ~v[r];
      u32 mono = kv >> 16;
      float val;
      if (mono == 0u) {
        val = -1e30f;
      } else {
        u16 hb = (u16)((mono & 0x8000u) ? (mono ^ 0x8000u) : (mono ^ 0xFFFFu));
        val = f16_from_bits(hb);
      }
      ov[r] = val;
      oi[r] = (float)(0xFFFFu - (kv & 0xFFFFu));
    }
  }
}

// ---------------- per-row top-k from stored f16 scores ----------------
__launch_bounds__(256, 4)
__global__ void topk_k(const f16* __restrict__ S, float* __restrict__ out) {
  int t = blockIdx.x, tid = threadIdx.x;
  __shared__ __align__(16) u32 key[4096];
  size_t base = soff(t);
  int nsort = (t <= 2047) ? 2048 : 4096;
  const uint4* src = (const uint4*)(S + base);
  for (int i = tid; i < (nsort >> 3); i += 256) {
    uint4 v4 = src[i];  // 8 f16 (may read past row's valid cols; masked below)
    u32 ww[4] = {v4.x, v4.y, v4.z, v4.w};
#pragma unroll
    for (int j = 0; j < 8; j++) {
      int s = i * 8 + j;
      u32 kk;
      if (s > t) {
        kk = 0xFFFFu - (u32)s;  // fill: mono16 = 0 sorts below all reals
      } else {
        u16 hb = (u16)(ww[j >> 1] >> ((j & 1) * 16));
        u32 mono = (hb & 0x8000u) ? (u32)(hb ^ 0xFFFFu) : (u32)(hb | 0x8000u);
        kk = (mono << 16) | (0xFFFFu - (u32)s);
      }
      key[s] = kk;
    }
  }
  __syncthreads();
  if (t <= 2047) sort_and_store<2048>(key, tid, t, out);
  else           sort_and_store<4096>(key, tid, t, out);
}

extern "C" void kernel_launch(void* const* d_in, const int* in_sizes, int n_in,
                              void* d_out, int out_size, void* d_ws, size_t ws_size,
                              hipStream_t stream) {
  const float* hs = (const float*)d_in[0];
  const float* qr = (const float*)d_in[1];
  const int* pos = (const int*)d_in[2];
  const float* Wq = (const float*)d_in[3];
  const float* Wk = (const float*)d_in[4];
  const float* Wp = (const float*)d_in[5];
  const float* gamma = (const float*)d_in[6];
  const float* beta = (const float*)d_in[7];
  char* ws = (char*)d_ws;
  // small buffers first, big streams last; total 99,221,504 B
  float* kraw = (float*)ws;                 //  2,097,152
  float* wsc = (float*)(ws + 2097152);      //  1,048,576
  f16* k16 = (f16*)(ws + 3145728);          //  1,048,576
  f16* kwT = (f16*)(ws + 4194304);          //  2,752,512  f16 [192][7168]
  f16* wqT = (f16*)(ws + 6946816);          // 25,165,824  f16 [8192][1536]
  f16* q16 = (f16*)(ws + 32112640);         // 67,108,864  f16 [4096][8192]
  // S overlays the (dead-by-then) kwT/wqT region: 8,650,752 f16 = 17,301,504 B
  f16* S = (f16*)(ws + 4194304);

  tcvt<<<dim3(256, 48), dim3(256), 0, stream>>>(Wq, wqT, QL, QD, QL, 0);
  tcvt<<<dim3(4, 224), dim3(256), 0, stream>>>(Wk, kwT, HID, HD, HID, 0);
  tcvt<<<dim3(2, 224), dim3(256), 0, stream>>>(Wp, kwT, HID, NH, HID, HD);
  gemm_kw<<<dim3(3, 64), dim3(256), 0, stream>>>(hs, kwT, kraw, wsc);
  ln_rope<<<dim3(1024), dim3(256), 0, stream>>>(kraw, pos, gamma, beta, k16);
  gemm_q<<<dim3(64, 32), dim3(256), 0, stream>>>(qr, wqT, q16);
  rope_q<<<dim3(4096), dim3(256), 0, stream>>>(q16, pos);
  scores4<<<dim3(1088), dim3(256), 0, stream>>>(q16, k16, wsc, S);
  topk_k<<<dim3(4096), dim3(256), 0, stream>>>(S, (float*)d_out);
}

// Round 6
// 802.850 us; speedup vs baseline: 1.1356x; 1.1356x over previous
//
#include <hip/hip_runtime.h>
#include <stdint.h>

#define TT 4096
#define HID 7168
#define QL 1536
#define NH 64
#define HD 128
#define QD 8192
#define KTOP 2048
#define WSCALE 0.011048543456039806f

typedef _Float16 f16;
typedef uint16_t u16;
typedef unsigned u32;
typedef __attribute__((ext_vector_type(4))) float f32x4;
typedef __attribute__((ext_vector_type(16))) float f32x16;
typedef __attribute__((ext_vector_type(8))) _Float16 f16x8;
typedef __attribute__((ext_vector_type(4))) _Float16 f16x4;

__device__ __forceinline__ void lds_load16(const void* g, void* l) {
  __builtin_amdgcn_global_load_lds(
      (const __attribute__((address_space(1))) unsigned*)g,
      (__attribute__((address_space(3))) unsigned*)l, 16, 0, 0);
}

__device__ __forceinline__ u16 f16_bits(f16 h) {
  union { f16 h; u16 u; } c; c.h = h; return c.u;
}
__device__ __forceinline__ float f16_from_bits(u16 u) {
  union { u16 u; f16 h; } c; c.u = u; return (float)c.h;
}

// packed-triangular row offset (elements); each row t gets roundup(t+1,128) slots.
__device__ __forceinline__ size_t soff(int t) {
  int b = t >> 7, r = t & 127;
  return (size_t)128u * ((size_t)(b + 1) * (size_t)(64 * b + r));
}

// ---------------- qr fp32 -> f16 ----------------
__global__ void cvt_qr(const float* __restrict__ in, f16* __restrict__ out) {
  int i = blockIdx.x * 256 + threadIdx.x;  // 8 elems per thread
  const float4* p = (const float4*)in + (size_t)i * 2;
  float4 a = p[0], b = p[1];
  f16x8 h = {(f16)a.x, (f16)a.y, (f16)a.z, (f16)a.w,
             (f16)b.x, (f16)b.y, (f16)b.z, (f16)b.w};
  *(f16x8*)(out + (size_t)i * 8) = h;
}

// ---------------- tiled transpose f32[R][C] -> f16 out[(c-icol0+orow0)][r] ----------------
__global__ void tcvt(const float* __restrict__ in, f16* __restrict__ out,
                     int R, int C, int ostride, int orow0, int icol0) {
  __shared__ float tile[32][33];
  int cb = blockIdx.x * 32, rb = blockIdx.y * 32;
  int tx = threadIdx.x & 31, ty = threadIdx.x >> 5;  // ty 0..7
  for (int i = 0; i < 32; i += 8)
    tile[ty + i][tx] = in[(size_t)(rb + ty + i) * C + icol0 + cb + tx];
  __syncthreads();
  for (int i = 0; i < 32; i += 8)
    out[(size_t)(cb + ty + i + orow0) * ostride + rb + tx] = (f16)tile[tx][ty + i];
}

// ---------------- q16 cols [col0,col0+4096) = f16(qr16 @ wqT_half^T)  (m97-style, both via gload_lds) ----
__launch_bounds__(256, 2)
__global__ void gemm_q2(const f16* __restrict__ A, const f16* __restrict__ B,
                        f16* __restrict__ C, int col0) {
  __shared__ __align__(16) f16 As[128 * 32];
  __shared__ __align__(16) f16 Bs[128 * 32];
  int tid = threadIdx.x, lane = tid & 63, wave = tid >> 6;
  int bm = blockIdx.y << 7, bn = blockIdx.x << 7;
  int wm = (wave & 1) << 6, wn = (wave >> 1) << 6;
  int sr = tid >> 2, sc = (tid & 3) * 8;
  const f16* ga = A + (size_t)(bm + sr) * QL + sc;
  const f16* gb = B + (size_t)(bn + sr) * QL + sc;
  f16* la = As + tid * 8;   // byte tid*16: linear wave-uniform + lane*16
  f16* lb = Bs + tid * 8;
  f32x4 acc[4][4] = {};
  for (int k0 = 0; k0 < QL; k0 += 32) {
    __syncthreads();
    lds_load16(ga + k0, la);
    lds_load16(ga + (size_t)64 * QL + k0, la + 2048);
    lds_load16(gb + k0, lb);
    lds_load16(gb + (size_t)64 * QL + k0, lb + 2048);
    __syncthreads();
    int ro = lane & 15, ko = (lane >> 4) << 3;
    f16x8 af[4], bf[4];
#pragma unroll
    for (int i = 0; i < 4; i++) af[i] = *(const f16x8*)(As + (wm + i * 16 + ro) * 32 + ko);
#pragma unroll
    for (int i = 0; i < 4; i++) bf[i] = *(const f16x8*)(Bs + (wn + i * 16 + ro) * 32 + ko);
#pragma unroll
    for (int mi = 0; mi < 4; mi++)
#pragma unroll
      for (int ni = 0; ni < 4; ni++)
        acc[mi][ni] = __builtin_amdgcn_mfma_f32_16x16x32_f16(af[mi], bf[ni], acc[mi][ni], 0, 0, 0);
  }
  int cr = (lane >> 4) << 2, cc = lane & 15;
#pragma unroll
  for (int mi = 0; mi < 4; mi++)
#pragma unroll
    for (int ni = 0; ni < 4; ni++) {
      int row = bm + wm + mi * 16 + cr;
      int col = col0 + bn + wn + ni * 16 + cc;
      f16* cp = C + (size_t)row * QD + col;
#pragma unroll
      for (int r = 0; r < 4; r++) cp[(size_t)r * QD] = (f16)acc[mi][ni][r];
    }
}

// ---------------- [kraw | w] = hs @ [Wk | Wproj]  (A fp32 via ds_write staging; 64x64, BK=64) ----------------
__launch_bounds__(256, 2)
__global__ void gemm_kw(const float* __restrict__ A, const f16* __restrict__ B,
                        float* __restrict__ kraw, float* __restrict__ wout) {
  __shared__ __align__(16) f16 As[64 * 64];
  __shared__ __align__(16) f16 Bs[64 * 64];
  int tid = threadIdx.x, lane = tid & 63, wave = tid >> 6;
  int bm = blockIdx.y << 6, bn = blockIdx.x << 6;
  int wm = (wave & 1) << 5, wn = (wave >> 1) << 5;
  const f16* gb = B + (size_t)(bn + (tid >> 3)) * HID + (tid & 7) * 8;
  f16* lB = Bs + wave * 512;
  int ar = tid >> 4, ac = (tid & 15) * 4;
  f32x4 acc[2][2] = {};
  for (int k0 = 0; k0 < HID; k0 += 64) {
    __syncthreads();
#pragma unroll
    for (int i = 0; i < 4; i++) {
      float4 v = *(const float4*)(A + (size_t)(bm + ar + i * 16) * HID + k0 + ac);
      f16x4 h = {(f16)v.x, (f16)v.y, (f16)v.z, (f16)v.w};
      *(f16x4*)(As + (ar + i * 16) * 64 + ac) = h;
    }
    lds_load16(gb + k0, lB);
    lds_load16(gb + (size_t)32 * HID + k0, lB + 2048);
    __syncthreads();
    int ro = lane & 15, ko = (lane >> 4) << 3;
    f16x8 af[2][2], bf[2][2];
#pragma unroll
    for (int i = 0; i < 2; i++)
#pragma unroll
      for (int kk = 0; kk < 2; kk++) {
        af[i][kk] = *(const f16x8*)(As + (wm + i * 16 + ro) * 64 + kk * 32 + ko);
        bf[i][kk] = *(const f16x8*)(Bs + (wn + i * 16 + ro) * 64 + kk * 32 + ko);
      }
#pragma unroll
    for (int mi = 0; mi < 2; mi++)
#pragma unroll
      for (int ni = 0; ni < 2; ni++)
#pragma unroll
        for (int kk = 0; kk < 2; kk++)
          acc[mi][ni] = __builtin_amdgcn_mfma_f32_16x16x32_f16(af[mi][kk], bf[ni][kk], acc[mi][ni], 0, 0, 0);
  }
  int cr = (lane >> 4) << 2, cc = lane & 15;
#pragma unroll
  for (int mi = 0; mi < 2; mi++)
#pragma unroll
    for (int ni = 0; ni < 2; ni++) {
      int row = bm + wm + mi * 16 + cr;
      int col = bn + wn + ni * 16 + cc;
#pragma unroll
      for (int r = 0; r < 4; r++) {
        float v = acc[mi][ni][r];
        int rr = row + r;
        if (col < HD) kraw[(size_t)rr * HD + col] = v;
        else          wout[(size_t)rr * NH + (col - HD)] = v * WSCALE;
      }
    }
}

// ---------------- layernorm + rope on k -> f16 ----------------
__global__ void ln_rope(const float* __restrict__ kraw, const int* __restrict__ pos,
                        const float* __restrict__ gamma, const float* __restrict__ beta,
                        f16* __restrict__ k16) {
  int row = (blockIdx.x << 2) + (threadIdx.x >> 6);
  int lane = threadIdx.x & 63;
  const float* kr = kraw + (size_t)row * HD;
  float2 x = ((const float2*)kr)[lane];
  float s = x.x + x.y, s2 = x.x * x.x + x.y * x.y;
  for (int off = 32; off; off >>= 1) { s += __shfl_down(s, off); s2 += __shfl_down(s2, off); }
  s = __shfl(s, 0); s2 = __shfl(s2, 0);
  float mu = s * (1.f / 128.f);
  float var = s2 * (1.f / 128.f) - mu * mu;
  float inv = rsqrtf(var + 1e-6f);
  float y0 = (x.x - mu) * inv * gamma[lane * 2] + beta[lane * 2];
  float y1 = (x.y - mu) * inv * gamma[lane * 2 + 1] + beta[lane * 2 + 1];
  float o0 = y0, o1 = y1;
  if (lane < 32) {
    float p = (float)pos[row];
    float invf = exp2f(-(float)lane * 0.41524101185942813f);  // 10000^(-2l/64)
    float ang = p * invf;
    float sn, cn;
    sincosf(ang, &sn, &cn);
    o0 = y0 * cn - y1 * sn;
    o1 = y0 * sn + y1 * cn;
  }
  k16[(size_t)row * HD + 2 * lane] = (f16)o0;
  k16[(size_t)row * HD + 2 * lane + 1] = (f16)o1;
}

// ---------------- rope on q16 in place (dims 0..63 of each head) ----------------
__global__ void rope_q(f16* __restrict__ q16, const int* __restrict__ pos) {
  int t = blockIdx.x, tid = threadIdx.x;
  __shared__ float cs[64];
  if (tid < 32) {
    float invf = exp2f(-(float)tid * 0.41524101185942813f);
    float ang = (float)pos[t] * invf;
    float sn, cn;
    sincosf(ang, &sn, &cn);
    cs[tid] = cn;
    cs[32 + tid] = sn;
  }
  __syncthreads();
  f16* row = q16 + (size_t)t * QD;
#pragma unroll
  for (int it = 0; it < 2; it++) {
    int u = it * 256 + tid;
    int h = u >> 3, c = u & 7;     // 64 heads x 8 chunks of 16B (dims 0..63)
    f16* p = row + h * HD + c * 8;
    f16x8 v = *(f16x8*)p;
#pragma unroll
    for (int j = 0; j < 4; j++) {
      int l = c * 4 + j;
      float cn = cs[l], sn = cs[32 + l];
      float x = (float)v[2 * j], y = (float)v[2 * j + 1];
      v[2 * j] = (f16)(x * cn - y * sn);
      v[2 * j + 1] = (f16)(x * sn + y * cn);
    }
    *(f16x8*)p = v;
  }
}

// ---------------- scores GEMM: 32 queries x 256 keys per block, K-frags in regs across 64 heads ----
// 4-buffer 3-deep counted-vmcnt pipeline over heads; compact active-block grid (1088 blocks).
// S stored f16 in packed-triangular rows (row t gets roundup(t+1,128) slots).
__launch_bounds__(256, 3)
__global__ void scores2(const f16* __restrict__ q16, const f16* __restrict__ k16,
                        const float* __restrict__ w, f16* __restrict__ S) {
  // compact enumeration of active (qt,kt) pairs + XCD-chunked bijective swizzle (1088 = 8*136)
  int bid = (int)blockIdx.x;
  bid = (bid & 7) * 136 + (bid >> 3);
  int g = 0;
  while (4 * (g + 1) * (g + 2) <= bid) g++;   // group g: qt in [8g,8g+7], each with g+1 key tiles
  int rem = bid - 4 * g * (g + 1);
  int qt = (g << 3) + rem / (g + 1);
  int kt = rem - (rem / (g + 1)) * (g + 1);
  int kt0 = kt << 8, qt0 = qt << 5;

  int tid = threadIdx.x, l = tid & 63, wid = tid >> 6;
  int q = l & 31, half = l >> 5;
  __shared__ __align__(16) f16 smem_q[4 * 4096];  // 4 x 8KB Q_h ring buffer; reused as store tile
  __shared__ float w_lds[2048];                   // w[h][q] (transposed)  8KB

  // stage per-query head weights (transposed for conflict-free broadcast reads)
  for (int i = tid; i < 2048; i += 256) {
    int hh = i & 63, qq = i >> 6;
    w_lds[hh * 32 + qq] = w[(size_t)(qt0 + qq) * NH + hh];
  }
  // K fragments into registers: wave wid owns keys kt0 + wid*64 .. +63 (2 M-tiles of 32)
  f16x8 kfr[2][8];
  {
    const f16* kb = k16 + (size_t)(kt0 + wid * 64 + q) * HD + half * 8;
#pragma unroll
    for (int mt = 0; mt < 2; mt++)
#pragma unroll
      for (int kk = 0; kk < 8; kk++)
        kfr[mt][kk] = *(const f16x8*)(kb + mt * 32 * HD + kk * 16);
  }
  __syncthreads();  // w_lds visible everywhere
  // make vmcnt state deterministic before the counted pipeline (kfr/w loads drained)
  asm volatile("s_waitcnt vmcnt(0)" ::: "memory");

  const f16* qbase = q16 + (size_t)qt0 * QD;
  auto stage = [&](int h) {  // 2 global_load_lds per thread; buf (h&3); linear LDS dest
    const f16* src = qbase + h * HD;
    f16* dst = smem_q + (h & 3) * 4096;
#pragma unroll
    for (int p = 0; p < 2; p++) {
      int u = p * 256 + tid;
      lds_load16(src + (size_t)(u & 31) * QD + (u >> 5) * 8, dst + u * 8);
    }
  };

  f32x16 s0 = {}, s1 = {};
  auto compute = [&](int h) {
    const f16* qb = smem_q + (h & 3) * 4096;
    f32x16 a0 = {}, a1 = {};
    __builtin_amdgcn_s_setprio(1);
#pragma unroll
    for (int kk = 0; kk < 8; kk++) {
      f16x8 qf = *(const f16x8*)(qb + ((kk * 2 + half) * 32 + q) * 8);
      a0 = __builtin_amdgcn_mfma_f32_32x32x16_f16(kfr[0][kk], qf, a0, 0, 0, 0);
      a1 = __builtin_amdgcn_mfma_f32_32x32x16_f16(kfr[1][kk], qf, a1, 0, 0, 0);
    }
    __builtin_amdgcn_s_setprio(0);
    float wv = w_lds[h * 32 + q];
#pragma unroll
    for (int r = 0; r < 16; r++) {
      s0[r] += wv * fmaxf(a0[r], 0.f);
      s1[r] += wv * fmaxf(a1[r], 0.f);
    }
  };

  stage(0); stage(1); stage(2);  // 6 loads in flight
  for (int h = 0; h < 61; h++) {
    // own stage(h) landed (others' too: their wait precedes their barrier)
    asm volatile("s_waitcnt vmcnt(4)" ::: "memory");
    __builtin_amdgcn_s_barrier();
    asm volatile("" ::: "memory");  // keep stage/ds_read on this side of the barrier
    stage(h + 3);                   // overwrites buf (h-1)&3: all reads done before barrier
    compute(h);
  }
  asm volatile("s_waitcnt vmcnt(4)" ::: "memory");
  __builtin_amdgcn_s_barrier();
  asm volatile("" ::: "memory");
  compute(61);
  asm volatile("s_waitcnt vmcnt(2)" ::: "memory");
  __builtin_amdgcn_s_barrier();
  asm volatile("" ::: "memory");
  compute(62);
  asm volatile("s_waitcnt vmcnt(0)" ::: "memory");
  __builtin_amdgcn_s_barrier();
  asm volatile("" ::: "memory");
  compute(63);

  // epilogue: transpose through LDS (XOR-swizzled, bufs 0-1 region) then coalesced f16 stores
  f16* st = smem_q;  // [32 q][256 sl] f16, 16KB; disjoint from buf3 (read by compute(63))
#pragma unroll
  for (int mt = 0; mt < 2; mt++)
#pragma unroll
    for (int r = 0; r < 16; r++) {
      int m = (r & 3) + ((r >> 2) << 3) + half * 4;  // key row within 32x32 tile
      int sl = wid * 64 + mt * 32 + m;
      float v = mt ? s1[r] : s0[r];
      if (!(v == v)) v = 0.f;                        // NaN scrub
      v = fminf(fmaxf(v, -60000.f), 60000.f);        // keep f16-finite
      u32 byte = (u32)(q * 512 + sl * 2) ^ (u32)((q & 7) << 4);
      *(f16*)((char*)st + byte) = (f16)v;
    }
  __syncthreads();
  {
    int rq = tid >> 3, c = tid & 7;    // 32 rows x 8 chunks of 64B
    int t = qt0 + rq;
    size_t base = soff(t) + (size_t)kt0;
    bool hi = (t - kt0) >= 128;        // whether cols 128..255 fit this row's slot
#pragma unroll
    for (int j = 0; j < 4; j++) {
      if (c < 4 || hi) {
        u32 byte = (u32)(rq * 512 + c * 64 + j * 16) ^ (u32)((rq & 7) << 4);
        uint4 v = *(uint4*)((char*)st + byte);
        *(uint4*)(S + base + c * 32 + j * 8) = v;
      }
    }
  }
}

// ---------------- register-resident bitonic sort (ascending on ~key) + store ----------------
template <int N>
__device__ __forceinline__ void sort_and_store(u32* key, int tid, int t, float* out) {
  constexpr int V = N / 256;  // 8 or 16 keys per thread
  u32 v[V];
#pragma unroll
  for (int r = 0; r < V; r += 4) {
    uint4 q4 = *(const uint4*)(key + tid * V + r);
    v[r] = ~q4.x; v[r + 1] = ~q4.y; v[r + 2] = ~q4.z; v[r + 3] = ~q4.w;
  }
#pragma unroll
  for (int k = 2; k <= N; k <<= 1) {
#pragma unroll
    for (int j = k >> 1; j > 0; j >>= 1) {
      if (j >= 64 * V) {
        // cross-wave pass via LDS
#pragma unroll
        for (int r = 0; r < V; r += 4) {
          uint4 q4 = {v[r], v[r + 1], v[r + 2], v[r + 3]};
          *(uint4*)(key + tid * V + r) = q4;
        }
        __syncthreads();
        for (int m = tid; m < N / 2; m += 256) {
          int i = ((m & ~(j - 1)) << 1) | (m & (j - 1));
          int l = i | j;
          bool up = ((i & k) == 0);
          u32 a = key[i], b = key[l];
          if (up ? (a > b) : (a < b)) { key[i] = b; key[l] = a; }
        }
        __syncthreads();
#pragma unroll
        for (int r = 0; r < V; r += 4) {
          uint4 q4 = *(const uint4*)(key + tid * V + r);
          v[r] = q4.x; v[r + 1] = q4.y; v[r + 2] = q4.z; v[r + 3] = q4.w;
        }
      } else if (j >= V) {
        // cross-lane pass via shuffle
        int lanej = j / V;
        bool takeMin = (((tid & lanej) == 0) == (((tid * V) & k) == 0));
#pragma unroll
        for (int r = 0; r < V; r++) {
          u32 o = __shfl_xor(v[r], lanej, 64);
          u32 mn = min(v[r], o), mx = max(v[r], o);
          v[r] = takeMin ? mn : mx;
        }
      } else {
        // intra-thread pass: pure VALU
#pragma unroll
        for (int r = 0; r < V; r++) {
          if ((r & j) == 0) {
            bool up = (((tid * V + r) & k) == 0);
            u32 a = v[r], b = v[r | j];
            u32 mn = min(a, b), mx = max(a, b);
            v[r] = up ? mn : mx;
            v[r | j] = up ? mx : mn;
          }
        }
      }
    }
  }
  // elements 0..KTOP-1 (ascending ~key = descending key) -> output
  if (tid * V < KTOP) {
    float* ov = out + (size_t)t * KTOP + tid * V;
    float* oi = out + (size_t)TT * KTOP + (size_t)t * KTOP + tid * V;
#pragma unroll
    for (int r = 0; r < V; r++) {
      u32 kv = ~v[r];
      u32 mono = kv >> 16;
      float val;
      if (mono == 0u) {
        val = -1e30f;
      } else {
        u16 hb = (u16)((mono & 0x8000u) ? (mono ^ 0x8000u) : (mono ^ 0xFFFFu));
        val = f16_from_bits(hb);
      }
      ov[r] = val;
      oi[r] = (float)(0xFFFFu - (kv & 0xFFFFu));
    }
  }
}

// ---------------- per-row top-k from stored f16 scores ----------------
__launch_bounds__(256, 4)
__global__ void topk_k(const f16* __restrict__ S, float* __restrict__ out) {
  int t = blockIdx.x, tid = threadIdx.x;
  __shared__ __align__(16) u32 key[4096];
  size_t base = soff(t);
  int nsort = (t <= 2047) ? 2048 : 4096;
  const uint4* src = (const uint4*)(S + base);
  for (int i = tid; i < (nsort >> 3); i += 256) {
    uint4 v4 = src[i];  // 8 f16 (may read past row's valid cols; masked below)
    u32 ww[4] = {v4.x, v4.y, v4.z, v4.w};
#pragma unroll
    for (int j = 0; j < 8; j++) {
      int s = i * 8 + j;
      u32 kk;
      if (s > t) {
        kk = 0xFFFFu - (u32)s;  // fill: mono16 = 0 sorts below all reals
      } else {
        u16 hb = (u16)(ww[j >> 1] >> ((j & 1) * 16));
        u32 mono = (hb & 0x8000u) ? (u32)(hb ^ 0xFFFFu) : (u32)(hb | 0x8000u);
        kk = (mono << 16) | (0xFFFFu - (u32)s);
      }
      key[s] = kk;
    }
  }
  __syncthreads();
  if (t <= 2047) sort_and_store<2048>(key, tid, t, out);
  else           sort_and_store<4096>(key, tid, t, out);
}

extern "C" void kernel_launch(void* const* d_in, const int* in_sizes, int n_in,
                              void* d_out, int out_size, void* d_ws, size_t ws_size,
                              hipStream_t stream) {
  const float* hs = (const float*)d_in[0];
  const float* qr = (const float*)d_in[1];
  const int* pos = (const int*)d_in[2];
  const float* Wq = (const float*)d_in[3];
  const float* Wk = (const float*)d_in[4];
  const float* Wp = (const float*)d_in[5];
  const float* gamma = (const float*)d_in[6];
  const float* beta = (const float*)d_in[7];
  char* ws = (char*)d_ws;
  // Layout (lifetime-disjoint overlays), peak 99,221,504 B:
  //  [0,12.58M)       qr16 f16 [4096][1536]   live: cvt_qr .. gemm_q2 (both halves)
  //  [12.58M,25.17M)  wqT_h f16 [4096][1536]  live: per-half tcvt .. gemm_q2 (reused)
  //  [0,2M)           kraw f32                live: gemm_kw .. ln_rope   (qr16 dead)
  //  [2M,3M)          wsc f32                 live: gemm_kw .. scores2   (qr16 dead)
  //  [3M,4M)          k16 f16                 live: ln_rope .. scores2   (qr16 dead)
  //  [4.19M,6.95M)    kwT f16 [192][7168]     live: tcvt_k .. gemm_kw    (qr16 dead)
  //  [4.19M,21.5M)    S f16 packed-tri        live: scores2 .. topk_k    (kwT/wqT_h dead)
  //  [32.11M,99.22M)  q16 f16 [4096][8192]    live: gemm_q2 .. scores2
  f16* qr16 = (f16*)ws;                     // 12,582,912
  f16* wqTh = (f16*)(ws + 12582912);        // 12,582,912
  float* kraw = (float*)ws;                 //  2,097,152
  float* wsc = (float*)(ws + 2097152);      //  1,048,576
  f16* k16 = (f16*)(ws + 3145728);          //  1,048,576
  f16* kwT = (f16*)(ws + 4194304);          //  2,752,512  f16 [192][7168]
  f16* S = (f16*)(ws + 4194304);            // 17,301,504
  f16* q16 = (f16*)(ws + 32112640);         // 67,108,864  f16 [4096][8192]

  // q path first (qr16/wqTh occupy the region kraw/kwT use later)
  cvt_qr<<<dim3(3072), dim3(256), 0, stream>>>(qr, qr16);
  tcvt<<<dim3(128, 48), dim3(256), 0, stream>>>(Wq, wqTh, QL, QD, QL, 0, 0);
  gemm_q2<<<dim3(32, 32), dim3(256), 0, stream>>>(qr16, wqTh, q16, 0);
  tcvt<<<dim3(128, 48), dim3(256), 0, stream>>>(Wq, wqTh, QL, QD, QL, 0, 4096);
  gemm_q2<<<dim3(32, 32), dim3(256), 0, stream>>>(qr16, wqTh, q16, 4096);
  rope_q<<<dim3(4096), dim3(256), 0, stream>>>(q16, pos);
  // k/w path (overwrites qr16 region, now dead)
  tcvt<<<dim3(4, 224), dim3(256), 0, stream>>>(Wk, kwT, HID, HD, HID, 0, 0);
  tcvt<<<dim3(2, 224), dim3(256), 0, stream>>>(Wp, kwT, HID, NH, HID, HD, 0);
  gemm_kw<<<dim3(3, 64), dim3(256), 0, stream>>>(hs, kwT, kraw, wsc);
  ln_rope<<<dim3(1024), dim3(256), 0, stream>>>(kraw, pos, gamma, beta, k16);
  // scores + topk (S overwrites kwT/wqTh regions, now dead)
  scores2<<<dim3(1088), dim3(256), 0, stream>>>(q16, k16, wsc, S);
  topk_k<<<dim3(4096), dim3(256), 0, stream>>>(S, (float*)d_out);
}

// Round 7
// 776.330 us; speedup vs baseline: 1.1744x; 1.0342x over previous
//
#include <hip/hip_runtime.h>
#include <stdint.h>

#define TT 4096
#define HID 7168
#define QL 1536
#define NH 64
#define HD 128
#define QD 8192
#define KTOP 2048
#define WSCALE 0.011048543456039806f

typedef _Float16 f16;
typedef uint16_t u16;
typedef unsigned u32;
typedef __attribute__((ext_vector_type(4))) float f32x4;
typedef __attribute__((ext_vector_type(16))) float f32x16;
typedef __attribute__((ext_vector_type(8))) _Float16 f16x8;
typedef __attribute__((ext_vector_type(4))) _Float16 f16x4;

__device__ __forceinline__ void lds_load16(const void* g, void* l) {
  __builtin_amdgcn_global_load_lds(
      (const __attribute__((address_space(1))) unsigned*)g,
      (__attribute__((address_space(3))) unsigned*)l, 16, 0, 0);
}

__device__ __forceinline__ u16 f16_bits(f16 h) {
  union { f16 h; u16 u; } c; c.h = h; return c.u;
}
__device__ __forceinline__ float f16_from_bits(u16 u) {
  union { u16 u; f16 h; } c; c.u = u; return (float)c.h;
}

// cross-lane xor exchange: DPP for 1/2 (VALU pipe), ds_swizzle for 4/8/16, bpermute for 32
__device__ __forceinline__ u32 xlane(u32 x, int lj) {
  if (lj == 1)  return (u32)__builtin_amdgcn_mov_dpp((int)x, 0xB1, 0xF, 0xF, true);  // quad_perm [1,0,3,2]
  if (lj == 2)  return (u32)__builtin_amdgcn_mov_dpp((int)x, 0x4E, 0xF, 0xF, true);  // quad_perm [2,3,0,1]
  if (lj == 4)  return (u32)__builtin_amdgcn_ds_swizzle((int)x, 0x101F);             // xor4
  if (lj == 8)  return (u32)__builtin_amdgcn_ds_swizzle((int)x, 0x201F);             // xor8
  if (lj == 16) return (u32)__builtin_amdgcn_ds_swizzle((int)x, 0x401F);             // xor16
  return (u32)__shfl_xor((int)x, lj, 64);                                            // 32
}

// packed-triangular row offset (elements); each row t gets roundup(t+1,128) slots.
__device__ __forceinline__ size_t soff(int t) {
  int b = t >> 7, r = t & 127;
  return (size_t)128u * ((size_t)(b + 1) * (size_t)(64 * b + r));
}

// ---------------- qr fp32 -> f16 ----------------
__global__ void cvt_qr(const float* __restrict__ in, f16* __restrict__ out) {
  int i = blockIdx.x * 256 + threadIdx.x;  // 8 elems per thread
  const float4* p = (const float4*)in + (size_t)i * 2;
  float4 a = p[0], b = p[1];
  f16x8 h = {(f16)a.x, (f16)a.y, (f16)a.z, (f16)a.w,
             (f16)b.x, (f16)b.y, (f16)b.z, (f16)b.w};
  *(f16x8*)(out + (size_t)i * 8) = h;
}

// ---------------- tiled transpose f32[R][C] -> f16 out[(c-icol0+orow0)][r] ----------------
__global__ void tcvt(const float* __restrict__ in, f16* __restrict__ out,
                     int R, int C, int ostride, int orow0, int icol0) {
  __shared__ float tile[32][33];
  int cb = blockIdx.x * 32, rb = blockIdx.y * 32;
  int tx = threadIdx.x & 31, ty = threadIdx.x >> 5;  // ty 0..7
  for (int i = 0; i < 32; i += 8)
    tile[ty + i][tx] = in[(size_t)(rb + ty + i) * C + icol0 + cb + tx];
  __syncthreads();
  for (int i = 0; i < 32; i += 8)
    out[(size_t)(cb + ty + i + orow0) * ostride + rb + tx] = (f16)tile[tx][ty + i];
}

// ---------------- q16 cols [col0,col0+4096) = f16(qr16 @ wqT_half^T) ----
// BK=64, both operands via global_load_lds; LDS granule-XOR swizzle (src pre-swizzled, linear dest):
// phys granule (row, c8) holds logical (row, c8^(row&7)) -> fragment reads are ~2-way (free).
__launch_bounds__(256, 2)
__global__ void gemm_q2(const f16* __restrict__ A, const f16* __restrict__ B,
                        f16* __restrict__ C, int col0) {
  __shared__ __align__(16) f16 As[128 * 64];
  __shared__ __align__(16) f16 Bs[128 * 64];
  int tid = threadIdx.x, lane = tid & 63, wave = tid >> 6;
  int bm = blockIdx.y << 7, bn = blockIdx.x << 7;
  int wm = (wave & 1) << 6, wn = (wave >> 1) << 6;
  int srow = tid >> 3;
  int sc8 = (tid & 7) ^ (srow & 7);                  // swizzled source granule
  const f16* ga = A + (size_t)(bm + srow) * QL + sc8 * 8;
  const f16* gb = B + (size_t)(bn + srow) * QL + sc8 * 8;
  f16* la = As + tid * 8;                            // linear dest; issue p at +p*2048
  f16* lb = Bs + tid * 8;
  f32x4 acc[4][4] = {};
  for (int k0 = 0; k0 < QL; k0 += 64) {
    __syncthreads();
#pragma unroll
    for (int p = 0; p < 4; p++) {
      lds_load16(ga + (size_t)(p * 32) * QL + k0, la + p * 2048);
      lds_load16(gb + (size_t)(p * 32) * QL + k0, lb + p * 2048);
    }
    __syncthreads();
    int ro = lane & 15, kg = lane >> 4;              // kg = granule within 32-k half
    f16x8 af[4][2], bf[4][2];
#pragma unroll
    for (int i = 0; i < 4; i++)
#pragma unroll
      for (int kk = 0; kk < 2; kk++) {
        int c8 = (kk * 4 + kg) ^ (ro & 7);           // swizzled read granule
        af[i][kk] = *(const f16x8*)(As + (wm + i * 16 + ro) * 64 + c8 * 8);
        bf[i][kk] = *(const f16x8*)(Bs + (wn + i * 16 + ro) * 64 + c8 * 8);
      }
#pragma unroll
    for (int kk = 0; kk < 2; kk++)
#pragma unroll
      for (int mi = 0; mi < 4; mi++)
#pragma unroll
        for (int ni = 0; ni < 4; ni++)
          acc[mi][ni] = __builtin_amdgcn_mfma_f32_16x16x32_f16(af[mi][kk], bf[ni][kk], acc[mi][ni], 0, 0, 0);
  }
  int cr = (lane >> 4) << 2, cc = lane & 15;
#pragma unroll
  for (int mi = 0; mi < 4; mi++)
#pragma unroll
    for (int ni = 0; ni < 4; ni++) {
      int row = bm + wm + mi * 16 + cr;
      int col = col0 + bn + wn + ni * 16 + cc;
      f16* cp = C + (size_t)row * QD + col;
#pragma unroll
      for (int r = 0; r < 4; r++) cp[(size_t)r * QD] = (f16)acc[mi][ni][r];
    }
}

// ---------------- [kraw | w] = hs @ [Wk | Wproj]  (64x64, BK=64, granule-XOR swizzled LDS) ----------------
__launch_bounds__(256, 2)
__global__ void gemm_kw(const float* __restrict__ A, const f16* __restrict__ B,
                        float* __restrict__ kraw, float* __restrict__ wout) {
  __shared__ __align__(16) f16 As[64 * 64];
  __shared__ __align__(16) f16 Bs[64 * 64];
  int tid = threadIdx.x, lane = tid & 63, wave = tid >> 6;
  int bm = blockIdx.y << 6, bn = blockIdx.x << 6;
  int wm = (wave & 1) << 5, wn = (wave >> 1) << 5;
  int srow = tid >> 3;
  int sc8 = (tid & 7) ^ (srow & 7);                  // swizzled source granule for B
  const f16* gb = B + (size_t)(bn + srow) * HID + sc8 * 8;
  f16* lB = Bs + wave * 512;                         // linear dest (granule = tid, +256 for issue2)
  int ar = tid >> 4, ac = (tid & 15) * 4;
  // A write-side swizzle: granule c8 = ac>>3, phys c8^(row&7), keep 4-f16 sub-offset
  int awc8 = (ac >> 3), awsub = ac & 7;
  f32x4 acc[2][2] = {};
  for (int k0 = 0; k0 < HID; k0 += 64) {
    __syncthreads();
#pragma unroll
    for (int i = 0; i < 4; i++) {
      float4 v = *(const float4*)(A + (size_t)(bm + ar + i * 16) * HID + k0 + ac);
      f16x4 h = {(f16)v.x, (f16)v.y, (f16)v.z, (f16)v.w};
      int row = ar + i * 16;
      *(f16x4*)(As + row * 64 + (awc8 ^ (row & 7)) * 8 + awsub) = h;
    }
    lds_load16(gb + k0, lB);
    lds_load16(gb + (size_t)32 * HID + k0, lB + 2048);
    __syncthreads();
    int ro = lane & 15, kg = lane >> 4;
    f16x8 af[2][2], bf[2][2];
#pragma unroll
    for (int i = 0; i < 2; i++)
#pragma unroll
      for (int kk = 0; kk < 2; kk++) {
        int c8 = (kk * 4 + kg) ^ (ro & 7);
        af[i][kk] = *(const f16x8*)(As + (wm + i * 16 + ro) * 64 + c8 * 8);
        bf[i][kk] = *(const f16x8*)(Bs + (wn + i * 16 + ro) * 64 + c8 * 8);
      }
#pragma unroll
    for (int mi = 0; mi < 2; mi++)
#pragma unroll
      for (int ni = 0; ni < 2; ni++)
#pragma unroll
        for (int kk = 0; kk < 2; kk++)
          acc[mi][ni] = __builtin_amdgcn_mfma_f32_16x16x32_f16(af[mi][kk], bf[ni][kk], acc[mi][ni], 0, 0, 0);
  }
  int cr = (lane >> 4) << 2, cc = lane & 15;
#pragma unroll
  for (int mi = 0; mi < 2; mi++)
#pragma unroll
    for (int ni = 0; ni < 2; ni++) {
      int row = bm + wm + mi * 16 + cr;
      int col = bn + wn + ni * 16 + cc;
#pragma unroll
      for (int r = 0; r < 4; r++) {
        float v = acc[mi][ni][r];
        int rr = row + r;
        if (col < HD) kraw[(size_t)rr * HD + col] = v;
        else          wout[(size_t)rr * NH + (col - HD)] = v * WSCALE;
      }
    }
}

// ---------------- layernorm + rope on k -> f16 ----------------
__global__ void ln_rope(const float* __restrict__ kraw, const int* __restrict__ pos,
                        const float* __restrict__ gamma, const float* __restrict__ beta,
                        f16* __restrict__ k16) {
  int row = (blockIdx.x << 2) + (threadIdx.x >> 6);
  int lane = threadIdx.x & 63;
  const float* kr = kraw + (size_t)row * HD;
  float2 x = ((const float2*)kr)[lane];
  float s = x.x + x.y, s2 = x.x * x.x + x.y * x.y;
  for (int off = 32; off; off >>= 1) { s += __shfl_down(s, off); s2 += __shfl_down(s2, off); }
  s = __shfl(s, 0); s2 = __shfl(s2, 0);
  float mu = s * (1.f / 128.f);
  float var = s2 * (1.f / 128.f) - mu * mu;
  float inv = rsqrtf(var + 1e-6f);
  float y0 = (x.x - mu) * inv * gamma[lane * 2] + beta[lane * 2];
  float y1 = (x.y - mu) * inv * gamma[lane * 2 + 1] + beta[lane * 2 + 1];
  float o0 = y0, o1 = y1;
  if (lane < 32) {
    float p = (float)pos[row];
    float invf = exp2f(-(float)lane * 0.41524101185942813f);  // 10000^(-2l/64)
    float ang = p * invf;
    float sn, cn;
    sincosf(ang, &sn, &cn);
    o0 = y0 * cn - y1 * sn;
    o1 = y0 * sn + y1 * cn;
  }
  k16[(size_t)row * HD + 2 * lane] = (f16)o0;
  k16[(size_t)row * HD + 2 * lane + 1] = (f16)o1;
}

// ---------------- rope on q16 in place (dims 0..63 of each head) ----------------
__global__ void rope_q(f16* __restrict__ q16, const int* __restrict__ pos) {
  int t = blockIdx.x, tid = threadIdx.x;
  __shared__ float cs[64];
  if (tid < 32) {
    float invf = exp2f(-(float)tid * 0.41524101185942813f);
    float ang = (float)pos[t] * invf;
    float sn, cn;
    sincosf(ang, &sn, &cn);
    cs[tid] = cn;
    cs[32 + tid] = sn;
  }
  __syncthreads();
  f16* row = q16 + (size_t)t * QD;
#pragma unroll
  for (int it = 0; it < 2; it++) {
    int u = it * 256 + tid;
    int h = u >> 3, c = u & 7;     // 64 heads x 8 chunks of 16B (dims 0..63)
    f16* p = row + h * HD + c * 8;
    f16x8 v = *(f16x8*)p;
#pragma unroll
    for (int j = 0; j < 4; j++) {
      int l = c * 4 + j;
      float cn = cs[l], sn = cs[32 + l];
      float x = (float)v[2 * j], y = (float)v[2 * j + 1];
      v[2 * j] = (f16)(x * cn - y * sn);
      v[2 * j + 1] = (f16)(x * sn + y * cn);
    }
    *(f16x8*)p = v;
  }
}

// ---------------- scores GEMM: 32 queries x 256 keys per block, K-frags in regs across 64 heads ----
// 4-buffer 3-deep counted-vmcnt pipeline over heads; compact active-block grid (1088 blocks).
// S stored f16 in packed-triangular rows (row t gets roundup(t+1,128) slots).
__launch_bounds__(256, 3)
__global__ void scores2(const f16* __restrict__ q16, const f16* __restrict__ k16,
                        const float* __restrict__ w, f16* __restrict__ S) {
  // compact enumeration of active (qt,kt) pairs + XCD-chunked bijective swizzle (1088 = 8*136)
  int bid = (int)blockIdx.x;
  bid = (bid & 7) * 136 + (bid >> 3);
  int g = 0;
  while (4 * (g + 1) * (g + 2) <= bid) g++;   // group g: qt in [8g,8g+7], each with g+1 key tiles
  int rem = bid - 4 * g * (g + 1);
  int qt = (g << 3) + rem / (g + 1);
  int kt = rem - (rem / (g + 1)) * (g + 1);
  int kt0 = kt << 8, qt0 = qt << 5;

  int tid = threadIdx.x, l = tid & 63, wid = tid >> 6;
  int q = l & 31, half = l >> 5;
  __shared__ __align__(16) f16 smem_q[4 * 4096];  // 4 x 8KB Q_h ring buffer; reused as store tile
  __shared__ float w_lds[2048];                   // w[h][q] (transposed)  8KB

  // stage per-query head weights (transposed for conflict-free broadcast reads)
  for (int i = tid; i < 2048; i += 256) {
    int hh = i & 63, qq = i >> 6;
    w_lds[hh * 32 + qq] = w[(size_t)(qt0 + qq) * NH + hh];
  }
  // K fragments into registers: wave wid owns keys kt0 + wid*64 .. +63 (2 M-tiles of 32)
  f16x8 kfr[2][8];
  {
    const f16* kb = k16 + (size_t)(kt0 + wid * 64 + q) * HD + half * 8;
#pragma unroll
    for (int mt = 0; mt < 2; mt++)
#pragma unroll
      for (int kk = 0; kk < 8; kk++)
        kfr[mt][kk] = *(const f16x8*)(kb + mt * 32 * HD + kk * 16);
  }
  __syncthreads();  // w_lds visible everywhere
  // make vmcnt state deterministic before the counted pipeline (kfr/w loads drained)
  asm volatile("s_waitcnt vmcnt(0)" ::: "memory");

  const f16* qbase = q16 + (size_t)qt0 * QD;
  auto stage = [&](int h) {  // 2 global_load_lds per thread; buf (h&3); linear LDS dest
    const f16* src = qbase + h * HD;
    f16* dst = smem_q + (h & 3) * 4096;
#pragma unroll
    for (int p = 0; p < 2; p++) {
      int u = p * 256 + tid;
      lds_load16(src + (size_t)(u & 31) * QD + (u >> 5) * 8, dst + u * 8);
    }
  };

  f32x16 s0 = {}, s1 = {};
  auto compute = [&](int h) {
    const f16* qb = smem_q + (h & 3) * 4096;
    f32x16 a0 = {}, a1 = {};
    __builtin_amdgcn_s_setprio(1);
#pragma unroll
    for (int kk = 0; kk < 8; kk++) {
      f16x8 qf = *(const f16x8*)(qb + ((kk * 2 + half) * 32 + q) * 8);
      a0 = __builtin_amdgcn_mfma_f32_32x32x16_f16(kfr[0][kk], qf, a0, 0, 0, 0);
      a1 = __builtin_amdgcn_mfma_f32_32x32x16_f16(kfr[1][kk], qf, a1, 0, 0, 0);
    }
    __builtin_amdgcn_s_setprio(0);
    float wv = w_lds[h * 32 + q];
#pragma unroll
    for (int r = 0; r < 16; r++) {
      s0[r] += wv * fmaxf(a0[r], 0.f);
      s1[r] += wv * fmaxf(a1[r], 0.f);
    }
  };

  stage(0); stage(1); stage(2);  // 6 loads in flight
  for (int h = 0; h < 61; h++) {
    // own stage(h) landed (others' too: their wait precedes their barrier)
    asm volatile("s_waitcnt vmcnt(4)" ::: "memory");
    __builtin_amdgcn_s_barrier();
    asm volatile("" ::: "memory");  // keep stage/ds_read on this side of the barrier
    stage(h + 3);                   // overwrites buf (h-1)&3: all reads done before barrier
    compute(h);
  }
  asm volatile("s_waitcnt vmcnt(4)" ::: "memory");
  __builtin_amdgcn_s_barrier();
  asm volatile("" ::: "memory");
  compute(61);
  asm volatile("s_waitcnt vmcnt(2)" ::: "memory");
  __builtin_amdgcn_s_barrier();
  asm volatile("" ::: "memory");
  compute(62);
  asm volatile("s_waitcnt vmcnt(0)" ::: "memory");
  __builtin_amdgcn_s_barrier();
  asm volatile("" ::: "memory");
  compute(63);

  // epilogue: transpose through LDS (XOR-swizzled, bufs 0-1 region) then coalesced f16 stores
  f16* st = smem_q;  // [32 q][256 sl] f16, 16KB; disjoint from buf3 (read by compute(63))
#pragma unroll
  for (int mt = 0; mt < 2; mt++)
#pragma unroll
    for (int r = 0; r < 16; r++) {
      int m = (r & 3) + ((r >> 2) << 3) + half * 4;  // key row within 32x32 tile
      int sl = wid * 64 + mt * 32 + m;
      float v = mt ? s1[r] : s0[r];
      if (!(v == v)) v = 0.f;                        // NaN scrub
      v = fminf(fmaxf(v, -60000.f), 60000.f);        // keep f16-finite
      u32 byte = (u32)(q * 512 + sl * 2) ^ (u32)((q & 7) << 4);
      *(f16*)((char*)st + byte) = (f16)v;
    }
  __syncthreads();
  {
    int rq = tid >> 3, c = tid & 7;    // 32 rows x 8 chunks of 64B
    int t = qt0 + rq;
    size_t base = soff(t) + (size_t)kt0;
    bool hi = (t - kt0) >= 128;        // whether cols 128..255 fit this row's slot
#pragma unroll
    for (int j = 0; j < 4; j++) {
      if (c < 4 || hi) {
        u32 byte = (u32)(rq * 512 + c * 64 + j * 16) ^ (u32)((rq & 7) << 4);
        uint4 v = *(uint4*)((char*)st + byte);
        *(uint4*)(S + base + c * 32 + j * 8) = v;
      }
    }
  }
}

// ---------------- register-resident bitonic sort (ascending on ~key) + store ----------------
template <int N>
__device__ __forceinline__ void sort_and_store(u32* key, int tid, int t, float* out) {
  constexpr int V = N / 256;  // 8 or 16 keys per thread
  u32 v[V];
#pragma unroll
  for (int r = 0; r < V; r += 4) {
    uint4 q4 = *(const uint4*)(key + tid * V + r);
    v[r] = ~q4.x; v[r + 1] = ~q4.y; v[r + 2] = ~q4.z; v[r + 3] = ~q4.w;
  }
#pragma unroll
  for (int k = 2; k <= N; k <<= 1) {
#pragma unroll
    for (int j = k >> 1; j > 0; j >>= 1) {
      if (j >= 64 * V) {
        // cross-wave pass via LDS
#pragma unroll
        for (int r = 0; r < V; r += 4) {
          uint4 q4 = {v[r], v[r + 1], v[r + 2], v[r + 3]};
          *(uint4*)(key + tid * V + r) = q4;
        }
        __syncthreads();
        for (int m = tid; m < N / 2; m += 256) {
          int i = ((m & ~(j - 1)) << 1) | (m & (j - 1));
          int l = i | j;
          bool up = ((i & k) == 0);
          u32 a = key[i], b = key[l];
          if (up ? (a > b) : (a < b)) { key[i] = b; key[l] = a; }
        }
        __syncthreads();
#pragma unroll
        for (int r = 0; r < V; r += 4) {
          uint4 q4 = *(const uint4*)(key + tid * V + r);
          v[r] = q4.x; v[r + 1] = q4.y; v[r + 2] = q4.z; v[r + 3] = q4.w;
        }
      } else if (j >= V) {
        // cross-lane pass: DPP / ds_swizzle / bpermute via xlane()
        int lanej = j / V;
        bool takeMin = (((tid & lanej) == 0) == (((tid * V) & k) == 0));
#pragma unroll
        for (int r = 0; r < V; r++) {
          u32 o = xlane(v[r], lanej);
          u32 mn = min(v[r], o), mx = max(v[r], o);
          v[r] = takeMin ? mn : mx;
        }
      } else {
        // intra-thread pass: pure VALU
#pragma unroll
        for (int r = 0; r < V; r++) {
          if ((r & j) == 0) {
            bool up = (((tid * V + r) & k) == 0);
            u32 a = v[r], b = v[r | j];
            u32 mn = min(a, b), mx = max(a, b);
            v[r] = up ? mn : mx;
            v[r | j] = up ? mx : mn;
          }
        }
      }
    }
  }
  // elements 0..KTOP-1 (ascending ~key = descending key) -> output
  if (tid * V < KTOP) {
    float* ov = out + (size_t)t * KTOP + tid * V;
    float* oi = out + (size_t)TT * KTOP + (size_t)t * KTOP + tid * V;
#pragma unroll
    for (int r = 0; r < V; r++) {
      u32 kv = ~v[r];
      u32 mono = kv >> 16;
      float val;
      if (mono == 0u) {
        val = -1e30f;
      } else {
        u16 hb = (u16)((mono & 0x8000u) ? (mono ^ 0x8000u) : (mono ^ 0xFFFFu));
        val = f16_from_bits(hb);
      }
      ov[r] = val;
      oi[r] = (float)(0xFFFFu - (kv & 0xFFFFu));
    }
  }
}

// ---------------- per-row top-k from stored f16 scores ----------------
__launch_bounds__(256, 4)
__global__ void topk_k(const f16* __restrict__ S, float* __restrict__ out) {
  int t = blockIdx.x, tid = threadIdx.x;
  __shared__ __align__(16) u32 key[4096];
  size_t base = soff(t);
  int nsort = (t <= 2047) ? 2048 : 4096;
  const uint4* src = (const uint4*)(S + base);
  for (int i = tid; i < (nsort >> 3); i += 256) {
    uint4 v4 = src[i];  // 8 f16 (may read past row's valid cols; masked below)
    u32 ww[4] = {v4.x, v4.y, v4.z, v4.w};
#pragma unroll
    for (int j = 0; j < 8; j++) {
      int s = i * 8 + j;
      u32 kk;
      if (s > t) {
        kk = 0xFFFFu - (u32)s;  // fill: mono16 = 0 sorts below all reals
      } else {
        u16 hb = (u16)(ww[j >> 1] >> ((j & 1) * 16));
        u32 mono = (hb & 0x8000u) ? (u32)(hb ^ 0xFFFFu) : (u32)(hb | 0x8000u);
        kk = (mono << 16) | (0xFFFFu - (u32)s);
      }
      key[s] = kk;
    }
  }
  __syncthreads();
  if (t <= 2047) sort_and_store<2048>(key, tid, t, out);
  else           sort_and_store<4096>(key, tid, t, out);
}

extern "C" void kernel_launch(void* const* d_in, const int* in_sizes, int n_in,
                              void* d_out, int out_size, void* d_ws, size_t ws_size,
                              hipStream_t stream) {
  const float* hs = (const float*)d_in[0];
  const float* qr = (const float*)d_in[1];
  const int* pos = (const int*)d_in[2];
  const float* Wq = (const float*)d_in[3];
  const float* Wk = (const float*)d_in[4];
  const float* Wp = (const float*)d_in[5];
  const float* gamma = (const float*)d_in[6];
  const float* beta = (const float*)d_in[7];
  char* ws = (char*)d_ws;
  // Layout (lifetime-disjoint overlays), peak 99,221,504 B:
  //  [0,12.58M)       qr16 f16 [4096][1536]   live: cvt_qr .. gemm_q2 (both halves)
  //  [12.58M,25.17M)  wqT_h f16 [4096][1536]  live: per-half tcvt .. gemm_q2 (reused)
  //  [0,2M)           kraw f32                live: gemm_kw .. ln_rope   (qr16 dead)
  //  [2M,3M)          wsc f32                 live: gemm_kw .. scores2   (qr16 dead)
  //  [3M,4M)          k16 f16                 live: ln_rope .. scores2   (qr16 dead)
  //  [4.19M,6.95M)    kwT f16 [192][7168]     live: tcvt_k .. gemm_kw    (qr16 dead)
  //  [4.19M,21.5M)    S f16 packed-tri        live: scores2 .. topk_k    (kwT/wqT_h dead)
  //  [32.11M,99.22M)  q16 f16 [4096][8192]    live: gemm_q2 .. scores2
  f16* qr16 = (f16*)ws;                     // 12,582,912
  f16* wqTh = (f16*)(ws + 12582912);        // 12,582,912
  float* kraw = (float*)ws;                 //  2,097,152
  float* wsc = (float*)(ws + 2097152);      //  1,048,576
  f16* k16 = (f16*)(ws + 3145728);          //  1,048,576
  f16* kwT = (f16*)(ws + 4194304);          //  2,752,512  f16 [192][7168]
  f16* S = (f16*)(ws + 4194304);            // 17,301,504
  f16* q16 = (f16*)(ws + 32112640);         // 67,108,864  f16 [4096][8192]

  // q path first (qr16/wqTh occupy the region kraw/kwT use later)
  cvt_qr<<<dim3(3072), dim3(256), 0, stream>>>(qr, qr16);
  tcvt<<<dim3(128, 48), dim3(256), 0, stream>>>(Wq, wqTh, QL, QD, QL, 0, 0);
  gemm_q2<<<dim3(32, 32), dim3(256), 0, stream>>>(qr16, wqTh, q16, 0);
  tcvt<<<dim3(128, 48), dim3(256), 0, stream>>>(Wq, wqTh, QL, QD, QL, 0, 4096);
  gemm_q2<<<dim3(32, 32), dim3(256), 0, stream>>>(qr16, wqTh, q16, 4096);
  rope_q<<<dim3(4096), dim3(256), 0, stream>>>(q16, pos);
  // k/w path (overwrites qr16 region, now dead)
  tcvt<<<dim3(4, 224), dim3(256), 0, stream>>>(Wk, kwT, HID, HD, HID, 0, 0);
  tcvt<<<dim3(2, 224), dim3(256), 0, stream>>>(Wp, kwT, HID, NH, HID, HD, 0);
  gemm_kw<<<dim3(3, 64), dim3(256), 0, stream>>>(hs, kwT, kraw, wsc);
  ln_rope<<<dim3(1024), dim3(256), 0, stream>>>(kraw, pos, gamma, beta, k16);
  // scores + topk (S overwrites kwT/wqTh regions, now dead)
  scores2<<<dim3(1088), dim3(256), 0, stream>>>(q16, k16, wsc, S);
  topk_k<<<dim3(4096), dim3(256), 0, stream>>>(S, (float*)d_out);
}